// Round 1
// 1403.484 us; speedup vs baseline: 1.0438x; 1.0438x over previous
//
#include <hip/hip_runtime.h>
#include <hip/hip_bf16.h>

#define N_SEG 4096
#define D 128

typedef __bf16 bf16;
typedef __attribute__((ext_vector_type(8))) __bf16 bf16x8;
typedef __attribute__((ext_vector_type(4))) __bf16 bf16x4;
typedef __attribute__((ext_vector_type(4))) float floatx4;

// ---------------------------------------------------------------------------
// Kernel 0: transpose + bf16-cast phi weights into ws:  wT[n][k] = w[k][n]
// ---------------------------------------------------------------------------
__global__ __launch_bounds__(256) void prep_weights(
    const float* __restrict__ w1, const float* __restrict__ w2,
    bf16* __restrict__ w1t, bf16* __restrict__ w2t) {
    int i = blockIdx.x * 256 + threadIdx.x;   // grid 64 -> 16384 threads
    int k = i >> 7, n = i & 127;
    w1t[n * 128 + k] = (bf16)w1[i];
    w2t[n * 128 + k] = (bf16)w2[i];
}

// ---------------------------------------------------------------------------
// Kernel 1a: segment bounds from sorted idx. bounds[s] = first i with idx[i]>=s,
// bounds[N_SEG] = n. One coalesced pass; gap-fill handles empty segments.
// ---------------------------------------------------------------------------
__global__ __launch_bounds__(256) void seg_bounds(
    const int* __restrict__ idx, int* __restrict__ bounds, int n) {
    int i = blockIdx.x * 256 + threadIdx.x;
    if (i >= n) return;
    int a = idx[i];
    if (i == 0) {
        for (int s = 0; s <= a; s++) bounds[s] = 0;
    } else {
        int p = idx[i - 1];
        for (int s = p + 1; s <= a; s++) bounds[s] = i;
    }
    if (i == n - 1) {
        for (int s = a + 1; s <= N_SEG; s++) bounds[s] = n;
    }
}

// ---------------------------------------------------------------------------
// Kernel 1b: segment sum, fp32. ONE BLOCK PER SEGMENT (idx sorted -> contiguous
// row range [bounds[s], bounds[s+1])). No atomics, no branches in inner loop.
// 256 threads: lane c4 = t&31 owns float4-column c4, rg = t>>5 strides rows by 8.
// 4-way unrolled -> 4 independent 16B loads in flight per thread.
// ---------------------------------------------------------------------------
__global__ __launch_bounds__(256) void seg_sum(
    const float* __restrict__ x, const int* __restrict__ bounds,
    float* __restrict__ xsum) {
    __shared__ float red[8][128];
    int s = blockIdx.x;
    int lo = bounds[s], hi = bounds[s + 1];
    int t = threadIdx.x;
    int c4 = t & 31, rg = t >> 5;
    const float4* x4 = (const float4*)x;
    float ax = 0.f, ay = 0.f, az = 0.f, aw = 0.f;
    int r = lo + rg;
    for (; r + 24 < hi; r += 32) {
        float4 v0 = x4[(size_t)(r     ) * 32 + c4];
        float4 v1 = x4[(size_t)(r +  8) * 32 + c4];
        float4 v2 = x4[(size_t)(r + 16) * 32 + c4];
        float4 v3 = x4[(size_t)(r + 24) * 32 + c4];
        ax += v0.x; ay += v0.y; az += v0.z; aw += v0.w;
        ax += v1.x; ay += v1.y; az += v1.z; aw += v1.w;
        ax += v2.x; ay += v2.y; az += v2.z; aw += v2.w;
        ax += v3.x; ay += v3.y; az += v3.z; aw += v3.w;
    }
    for (; r < hi; r += 8) {
        float4 v = x4[(size_t)r * 32 + c4];
        ax += v.x; ay += v.y; az += v.z; aw += v.w;
    }
    *(float4*)&red[rg][c4 * 4] = make_float4(ax, ay, az, aw);
    __syncthreads();
    if (t < 128) {
        float a = 0.f;
#pragma unroll
        for (int i = 0; i < 8; i++) a += red[i][t];
        xsum[(size_t)s * 128 + t] = a;
    }
}

// ---------------------------------------------------------------------------
// Kernel 2: rho MLP on x_sum [4096,128] -> rho_sum, full fp32 (accuracy on the
// large-magnitude path). 8 rows/block, 256 threads: c = t&127, 4 rows each.
// ---------------------------------------------------------------------------
__global__ __launch_bounds__(256) void rho_mlp(
    const float* __restrict__ xsum,
    const float* __restrict__ w1, const float* __restrict__ b1,
    const float* __restrict__ w2, const float* __restrict__ b2,
    float* __restrict__ rho) {
    __shared__ float xs[8][128];
    __shared__ float hs[8][128];
    int t = threadIdx.x;
    int r0 = blockIdx.x * 8;
    for (int i = t; i < 8 * 128; i += 256) xs[i >> 7][i & 127] = xsum[(size_t)r0 * 128 + i];
    __syncthreads();
    int c = t & 127, rg = t >> 7;   // rg in {0,1}, rows rg*4+p
    float acc[4];
#pragma unroll
    for (int p = 0; p < 4; p++) acc[p] = b1[c];
    for (int k = 0; k < 128; k++) {
        float w = w1[k * 128 + c];
#pragma unroll
        for (int p = 0; p < 4; p++) acc[p] += xs[rg * 4 + p][k] * w;
    }
#pragma unroll
    for (int p = 0; p < 4; p++) hs[rg * 4 + p][c] = fmaxf(acc[p], 0.f);
    __syncthreads();
#pragma unroll
    for (int p = 0; p < 4; p++) acc[p] = b2[c];
    for (int k = 0; k < 128; k++) {
        float w = w2[k * 128 + c];
#pragma unroll
        for (int p = 0; p < 4; p++) acc[p] += hs[rg * 4 + p][k] * w;
    }
#pragma unroll
    for (int p = 0; p < 4; p++) rho[(size_t)(r0 + rg * 4 + p) * 128 + c] = acc[p];
}

// ---------------------------------------------------------------------------
// Kernel 3: out = MLP_phi(x) + rho_sum[idx], bf16 MFMA 16x16x32.
// BM=128 rows/block, 512 threads = 8 waves; wave w owns rows [16w,16w+16):
// it stages them, GEMM1s them, writes h back into the same LDS strip, GEMM2s,
// gathers rho and stores. Strips are wave-private -> NO __syncthreads at all.
// Weights read as B-frags directly from global (w1t/w2t bf16 [n][k], L2-hot).
// v2: (a) all 8 staging loads issued before any cvt/ds_write (8KB/wave in
// flight); (b) nontemporal x loads + out stores so streaming traffic doesn't
// evict the 64KB of weights from L1/L2.
// LDS: x-tile 128 x (128+8 pad) bf16 = 34 KB (pad -> 2-way bank alias, free).
// ---------------------------------------------------------------------------
__global__ __launch_bounds__(512, 2) void phi_fused(
    const float* __restrict__ x, const int* __restrict__ idx,
    const bf16* __restrict__ w1t, const float* __restrict__ b1,
    const bf16* __restrict__ w2t, const float* __restrict__ b2,
    const float* __restrict__ rho, float* __restrict__ out, int n) {
    __shared__ bf16 xt[128][136];
    int t    = threadIdx.x;
    int wv   = t >> 6;        // wave 0..7
    int lane = t & 63;
    int m    = lane & 15;     // A-row / C-col lane index
    int q    = lane >> 4;     // quad 0..3
    long long r0 = (long long)blockIdx.x * 128;

    // ---- stage x tile (fp32 -> bf16). thread t covers row t>>2 (wave-own strip)
    {
        int row = t >> 2;
        long long grow = r0 + row;
        const floatx4* x4 = (const floatx4*)x;
        bool ok = grow < (long long)n;
        floatx4 v[8];
#pragma unroll
        for (int i = 0; i < 8; i++) {
            v[i] = (floatx4){0.f, 0.f, 0.f, 0.f};
            if (ok) v[i] = __builtin_nontemporal_load(&x4[grow * 32 + (t & 3) + 4 * i]);
        }
#pragma unroll
        for (int i = 0; i < 8; i++) {
            int c4 = (t & 3) + 4 * i;
            bf16x4 pv = {(bf16)v[i].x, (bf16)v[i].y, (bf16)v[i].z, (bf16)v[i].w};
            *(bf16x4*)&xt[row][c4 * 4] = pv;   // 8B aligned ds_write_b64
        }
    }
    const int srow0 = 16 * wv;

    // ---- GEMM1: h = relu(x @ w1 + b1), accumulate C-layout
    floatx4 acc1[8];
#pragma unroll
    for (int nt = 0; nt < 8; nt++) acc1[nt] = (floatx4){0.f, 0.f, 0.f, 0.f};
#pragma unroll
    for (int kt = 0; kt < 4; kt++) {
        bf16x8 a = *(const bf16x8*)&xt[srow0 + m][kt * 32 + q * 8];
#pragma unroll
        for (int nt = 0; nt < 8; nt++) {
            bf16x8 b = *(const bf16x8*)&w1t[(size_t)(nt * 16 + m) * 128 + kt * 32 + q * 8];
            acc1[nt] = __builtin_amdgcn_mfma_f32_16x16x32_bf16(a, b, acc1[nt], 0, 0, 0);
        }
    }
    // ---- bias + relu, write h back into own LDS strip in A-layout
#pragma unroll
    for (int nt = 0; nt < 8; nt++) {
        int col = nt * 16 + m;
        float bv = b1[col];
#pragma unroll
        for (int r = 0; r < 4; r++) {
            float h = fmaxf(acc1[nt][r] + bv, 0.f);
            xt[srow0 + q * 4 + r][col] = (bf16)h;
        }
    }
    // ---- GEMM2: y = h @ w2
    floatx4 acc2[8];
#pragma unroll
    for (int nt = 0; nt < 8; nt++) acc2[nt] = (floatx4){0.f, 0.f, 0.f, 0.f};
#pragma unroll
    for (int kt = 0; kt < 4; kt++) {
        bf16x8 a = *(const bf16x8*)&xt[srow0 + m][kt * 32 + q * 8];
#pragma unroll
        for (int nt = 0; nt < 8; nt++) {
            bf16x8 b = *(const bf16x8*)&w2t[(size_t)(nt * 16 + m) * 128 + kt * 32 + q * 8];
            acc2[nt] = __builtin_amdgcn_mfma_f32_16x16x32_bf16(a, b, acc2[nt], 0, 0, 0);
        }
    }
    // ---- epilogue: + b2 + rho_sum[idx[row]], store
    long long strip0 = r0 + srow0;
    long long ir = strip0 + m; if (ir > n - 1) ir = n - 1;
    int idxv = idx[ir];
    int seg[4];
#pragma unroll
    for (int r = 0; r < 4; r++) seg[r] = __shfl(idxv, q * 4 + r, 64);
#pragma unroll
    for (int nt = 0; nt < 8; nt++) {
        int col = nt * 16 + m;
        float b2v = b2[col];
#pragma unroll
        for (int r = 0; r < 4; r++) {
            long long grow = strip0 + q * 4 + r;
            if (grow < n) {
                float rv = rho[(size_t)seg[r] * 128 + col];
                __builtin_nontemporal_store(acc2[nt][r] + b2v + rv, &out[grow * 128 + col]);
            }
        }
    }
}

// ---------------------------------------------------------------------------
extern "C" void kernel_launch(void* const* d_in, const int* in_sizes, int n_in,
                              void* d_out, int out_size, void* d_ws, size_t ws_size,
                              hipStream_t stream) {
    const float* x      = (const float*)d_in[0];
    const int*   idx    = (const int*)d_in[1];
    const float* phi_w1 = (const float*)d_in[2];
    const float* phi_b1 = (const float*)d_in[3];
    const float* phi_w2 = (const float*)d_in[4];
    const float* phi_b2 = (const float*)d_in[5];
    const float* rho_w1 = (const float*)d_in[6];
    const float* rho_b1 = (const float*)d_in[7];
    const float* rho_w2 = (const float*)d_in[8];
    const float* rho_b2 = (const float*)d_in[9];
    float* out = (float*)d_out;
    int n = in_sizes[0] / D;   // 1,000,000

    char*  ws      = (char*)d_ws;
    float* xsum    = (float*)ws;                                   // 2 MB
    float* rho_sum = (float*)(ws + (size_t)N_SEG * D * 4);         // 2 MB
    bf16*  w1t     = (bf16*)(ws + 2 * (size_t)N_SEG * D * 4);      // 32 KB
    bf16*  w2t     = w1t + 128 * 128;                              // 32 KB
    int*   bounds  = (int*)(ws + 2 * (size_t)N_SEG * D * 4 + 2 * 128 * 128 * 2);  // 16.4 KB

    prep_weights<<<64, 256, 0, stream>>>(phi_w1, phi_w2, w1t, w2t);
    seg_bounds<<<(n + 255) / 256, 256, 0, stream>>>(idx, bounds, n);
    seg_sum<<<N_SEG, 256, 0, stream>>>(x, bounds, xsum);
    rho_mlp<<<N_SEG / 8, 256, 0, stream>>>(xsum, rho_w1, rho_b1, rho_w2, rho_b2, rho_sum);
    phi_fused<<<(n + 127) / 128, 512, 0, stream>>>(x, idx, w1t, phi_b1, w2t, phi_b2,
                                                   rho_sum, out, n);
}